// Round 10
// baseline (196.105 us; speedup 1.0000x reference)
//
#include <hip/hip_runtime.h>

#define NROW 6
#define NCOL 6
#define BATCH 1024
#define NSITE 36

// LDS bank-conflict swizzle: XOR dword-addr bits [4:2] with bits [7:5].
// Preserves bits [1:0]; constant within any aligned 4-dword window; SWZ(0)==0.
__device__ __forceinline__ int SWZ(int a) { return a ^ (((a >> 5) & 7) << 2); }

// Wave-uniform scalar-memory pointer: address_space(4) = AMDGPU constant.
// Scalar float loads at uniform offsets merge into s_load_dwordx4/x16 (SMEM
// pipe, one fetch per wave). R4 (LDS-M), R7 (VMEM-M) both regressed: M stays
// on SMEM. R8 proved v_pk_fma_f32 does NOT double FP32 rate on gfx950 —
// the ~72us VALU busy time is the FP32 issue floor for this decomposition.
typedef const float __attribute__((address_space(4))) * fcp;

__device__ __forceinline__ fcp msel(const float* Tm, int step,
                                    unsigned long long sm) {
    int spin = (int)((sm >> step) & 1ull);
    return (fcp)(unsigned long long)(const void*)
        (Tm + (size_t)(step * 2 + spin) * 256);
}

// Pre-transpose T[site][spin][u=x][r=gp][d=z][l=g] into
// Tm[(site*2+spin)*256 + (gp*4+z)*16 + (g*4+x)]  (73,728 B in d_ws).
__global__ void peps_reorder_kernel(const float* __restrict__ T,
                                    float* __restrict__ Tm)
{
    int idx = blockIdx.x * 256 + threadIdx.x;   // [0, 18432)
    if (idx >= NSITE * 2 * 256) return;
    int i  = idx & 15;          // i = g*4 + x
    int o  = (idx >> 4) & 15;   // o = gp*4 + z
    int sp = (idx >> 8) & 1;
    int st = idx >> 9;
    int g = i >> 2, x = i & 3, gp = o >> 2, z = o & 3;
    Tm[idx] = T[st * 512 + sp * 256 + x * 64 + gp * 16 + z * 4 + g];
}

// Fused middle-row pair (c=0)+(c=1) — VERBATIM R2 (harness-verified in this
// exact fixed-slot+SWZ layout). Reads 4 quads from plane 0 (16 floats),
// applies both matrices register-resident, writes 16 quads across 4 planes.
// Eliminates c0's 16-quad write + c1's 16-quad read + one barrier per row.
// In-place safe: thread t's read set (base=t<<4, plane 0) is inside its own
// write set; bases disjoint across threads; per-thread LDS ops are in-order.
__device__ __forceinline__ void mid_first(float* __restrict__ W, fcp M0,
                                          fcp M1, int base)
{
    float U[4][4];               // [x1][x0]
    #pragma unroll
    for (int x1 = 0; x1 < 4; ++x1) {
        float4 q = *(const float4*)&W[SWZ(base + 4 * x1)];   // g=0 plane
        U[x1][0] = q.x; U[x1][1] = q.y; U[x1][2] = q.z; U[x1][3] = q.w;
    }
    float V[4][4][4];            // [gp][z0][x1]
    #pragma unroll
    for (int gp = 0; gp < 4; ++gp)
        #pragma unroll
        for (int z0 = 0; z0 < 4; ++z0)
            #pragma unroll
            for (int x1 = 0; x1 < 4; ++x1) {
                float acc = 0.f;
                #pragma unroll
                for (int x0 = 0; x0 < 4; ++x0)
                    acc += M0[(gp * 4 + z0) * 16 + x0] * U[x1][x0];
                V[gp][z0][x1] = acc;
            }
    #pragma unroll
    for (int gp1 = 0; gp1 < 4; ++gp1)
        #pragma unroll
        for (int z1 = 0; z1 < 4; ++z1) {
            float o[4];
            #pragma unroll
            for (int z0 = 0; z0 < 4; ++z0) {
                float acc = 0.f;
                #pragma unroll
                for (int gp = 0; gp < 4; ++gp)
                    #pragma unroll
                    for (int x1 = 0; x1 < 4; ++x1)
                        acc += M1[(gp1 * 4 + z1) * 16 + gp * 4 + x1]
                             * V[gp][z0][x1];
                o[z0] = acc;
            }
            *(float4*)&W[gp1 * 4096 + SWZ(base + 4 * z1)] =
                make_float4(o[0], o[1], o[2], o[3]);
        }
}

// One MIDDLE-ROW step body (c>=2), 4 SPECTATORS PER THREAD (u = 4t..4t+3) —
// verbatim R0/R9 (harness-verified).
template<int GIN, int GOUT>
__device__ __forceinline__ void do_step4(float* __restrict__ W, const fcp Msf,
                                         const int* __restrict__ A)
{
    float in_s[4][16];           // [spectator][g*4+x]
    #pragma unroll
    for (int g = 0; g < GIN; ++g)
        #pragma unroll
        for (int x = 0; x < 4; ++x) {
            float4 q = *(const float4*)&W[A[x] + g * 4096];
            in_s[0][g*4+x] = q.x; in_s[1][g*4+x] = q.y;
            in_s[2][g*4+x] = q.z; in_s[3][g*4+x] = q.w;
        }
    #pragma unroll
    for (int gp = 0; gp < GOUT; ++gp) {
        float a[4][4];
        #pragma unroll
        for (int z = 0; z < 4; ++z) {
            const int mb = (gp * 4 + z) * 16;
            #pragma unroll
            for (int i = 0; i < 4; ++i) a[z][i] = 0.f;
            #pragma unroll
            for (int g = 0; g < GIN; ++g)
                #pragma unroll
                for (int x = 0; x < 4; ++x) {
                    const float m = Msf[mb + g * 4 + x];
                    #pragma unroll
                    for (int i = 0; i < 4; ++i)
                        a[z][i] += m * in_s[i][g*4+x];
                }
        }
        #pragma unroll
        for (int z = 0; z < 4; ++z)
            *(float4*)&W[A[z] + gp * 4096] =
                make_float4(a[z][0], a[z][1], a[z][2], a[z][3]);
    }
}

// R10 = R9 + fused (c0,c1) in rows 1..4 (mid_first, R2-verified):
//   row 0     : R2's fused chain (3 cheap phases)
//   rows 1..4 : fused(c0,c1) + c2..c5 in-place steps — 5 phases/row (was 6)
//   row 5     : R2's fused chain (3 tiny phases)
// Same layout (state idx = g*4096 + SWZ(sum slot_j*4^j)), same SWZ, same M
// path (SMEM), 2 blocks/CU. Phases: 30 -> 26; rows 1-4 LDS traffic -24%
// (c0-write + c1-read round trip eliminated).
__global__ __launch_bounds__(256, 2)
void peps_amp_kernel(const int* __restrict__ X, const float* __restrict__ Tm,
                     float* __restrict__ out)
{
    __shared__ float W[16384];   // 65536 B exactly (4^7 fixed-slot state)

    const int b = blockIdx.x;
    const int t = threadIdx.x;
    const int u0 = 4 * t;        // this thread's spectators: u0..u0+3
    const int* xrow = X + b * NSITE;

    // PHYS=2: pack the 36 spins into one scalar 64-bit mask (SGPR-resident
    // so every Tm address below is provably wave-uniform).
    unsigned long long sm = 0ull;
    const int4* xp = (const int4*)xrow;
    #pragma unroll
    for (int k = 0; k < 9; ++k) {
        int4 v = xp[k];
        sm |= ((unsigned long long)(v.x & 1)) << (4 * k + 0);
        sm |= ((unsigned long long)(v.y & 1)) << (4 * k + 1);
        sm |= ((unsigned long long)(v.z & 1)) << (4 * k + 2);
        sm |= ((unsigned long long)(v.w & 1)) << (4 * k + 3);
    }
    {
        unsigned lo = __builtin_amdgcn_readfirstlane((int)(sm & 0xffffffffull));
        unsigned hi = __builtin_amdgcn_readfirstlane((int)(sm >> 32));
        sm = ((unsigned long long)hi << 32) | lo;
    }

    // ---- row 0 (R2-verified): (0,0)+(0,1) by thread 0 ----
    if (t == 0) {
        fcp M0 = msel(Tm, 0, sm), M1 = msel(Tm, 1, sm);
        float V[4][4];           // [gp][z0]  (seed state == 1.0)
        #pragma unroll
        for (int gp = 0; gp < 4; ++gp)
            #pragma unroll
            for (int z0 = 0; z0 < 4; ++z0)
                V[gp][z0] = M0[(gp * 4 + z0) * 16];
        #pragma unroll
        for (int gp1 = 0; gp1 < 4; ++gp1)
            #pragma unroll
            for (int z1 = 0; z1 < 4; ++z1) {
                float o[4];
                #pragma unroll
                for (int z0 = 0; z0 < 4; ++z0) {
                    float acc = 0.f;
                    #pragma unroll
                    for (int gp = 0; gp < 4; ++gp)
                        acc += M1[(gp1 * 4 + z1) * 16 + gp * 4] * V[gp][z0];
                    o[z0] = acc;
                }
                *(float4*)&W[gp1 * 4096 + SWZ(4 * z1)] =
                    make_float4(o[0], o[1], o[2], o[3]);
            }
    }
    __syncthreads();
    // ---- row 0: (0,2)+(0,3) by 16 threads (t = z0 + 4*z1) ----
    if (t < 16) {
        fcp M2 = msel(Tm, 2, sm), M3 = msel(Tm, 3, sm);
        float U[4];
        #pragma unroll
        for (int g = 0; g < 4; ++g) U[g] = W[g * 4096 + SWZ(t)];
        float V[4][4];           // [gp][z2]
        #pragma unroll
        for (int gp = 0; gp < 4; ++gp)
            #pragma unroll
            for (int z2 = 0; z2 < 4; ++z2) {
                float acc = 0.f;
                #pragma unroll
                for (int g = 0; g < 4; ++g)
                    acc += M2[(gp * 4 + z2) * 16 + g * 4] * U[g];
                V[gp][z2] = acc;
            }
        #pragma unroll
        for (int gp3 = 0; gp3 < 4; ++gp3)
            #pragma unroll
            for (int z3 = 0; z3 < 4; ++z3)
                #pragma unroll
                for (int z2 = 0; z2 < 4; ++z2) {
                    float acc = 0.f;
                    #pragma unroll
                    for (int gp = 0; gp < 4; ++gp)
                        acc += M3[(gp3 * 4 + z3) * 16 + gp * 4] * V[gp][z2];
                    W[gp3 * 4096 + SWZ(t + 16 * z2 + 64 * z3)] = acc;
                }
    }
    __syncthreads();
    // ---- row 0: (0,4)+(0,5) by all 256 threads (g collapses -> plane 0) --
    {
        fcp M4 = msel(Tm, 4, sm), M5 = msel(Tm, 5, sm);
        float U[4];
        #pragma unroll
        for (int g = 0; g < 4; ++g) U[g] = W[g * 4096 + SWZ(t)];
        float V[4][4];           // [gp][z4]
        #pragma unroll
        for (int gp = 0; gp < 4; ++gp)
            #pragma unroll
            for (int z4 = 0; z4 < 4; ++z4) {
                float acc = 0.f;
                #pragma unroll
                for (int g = 0; g < 4; ++g)
                    acc += M4[(gp * 4 + z4) * 16 + g * 4] * U[g];
                V[gp][z4] = acc;
            }
        #pragma unroll
        for (int z5 = 0; z5 < 4; ++z5)
            #pragma unroll
            for (int z4 = 0; z4 < 4; ++z4) {
                float acc = 0.f;
                #pragma unroll
                for (int gp = 0; gp < 4; ++gp)
                    acc += M5[z5 * 16 + gp * 4] * V[gp][z4];
                W[SWZ(t + 256 * z4 + 1024 * z5)] = acc;    // plane 0
            }
    }

    // ---- rows 1..4: fused(c0,c1) + in-place c2..c5, 5 barriers/row ----
    int step = 6;
    for (int row = 1; row <= 4; ++row) {
        {
            fcp Ma = msel(Tm, step, sm);
            fcp Mb = msel(Tm, step + 1, sm);
            __syncthreads();
            mid_first(W, Ma, Mb, t << 4);
            step += 2;
        }
        for (int c = 2; c < NCOL; ++c, ++step) {
            const int lowb = 2 * c;
            const int p4c = 1 << (2 * c);
            const int lowmask = (1 << lowb) - 1;
            const fcp Msf = msel(Tm, step, sm);

            __syncthreads();     // the ONLY barrier per step

            int A[4];
            const int mr0 = ((u0 >> lowb) << (2 * c + 2)) | (u0 & lowmask);
            #pragma unroll
            for (int d = 0; d < 4; ++d) A[d] = SWZ(d * p4c + mr0);

            if (c < NCOL - 1) do_step4<4,4>(W, Msf, A);
            else              do_step4<4,1>(W, Msf, A);
        }
    }

    // ---- row 5 (R2-verified): (5,0)+(5,1) by all 256 threads ----
    __syncthreads();
    {
        fcp M0 = msel(Tm, 30, sm), M1 = msel(Tm, 31, sm);
        const int base = t << 4;
        float V[4][4];           // [gp][x1]
        #pragma unroll
        for (int x1 = 0; x1 < 4; ++x1) {
            float4 q = *(const float4*)&W[SWZ(base + 4 * x1)];
            float U[4] = {q.x, q.y, q.z, q.w};
            #pragma unroll
            for (int gp = 0; gp < 4; ++gp) {
                float acc = 0.f;
                #pragma unroll
                for (int x0 = 0; x0 < 4; ++x0)
                    acc += M0[gp * 64 + x0] * U[x0];
                V[gp][x1] = acc;
            }
        }
        #pragma unroll
        for (int gp1 = 0; gp1 < 4; ++gp1) {
            float acc = 0.f;
            #pragma unroll
            for (int gp = 0; gp < 4; ++gp)
                #pragma unroll
                for (int x1 = 0; x1 < 4; ++x1)
                    acc += M1[gp1 * 64 + gp * 4 + x1] * V[gp][x1];
            W[gp1 * 4096 + SWZ(base)] = acc;
        }
    }
    __syncthreads();
    // ---- row 5: (5,2)+(5,3) by 16 threads (t = x4 + 4*x5) ----
    if (t < 16) {
        fcp M2 = msel(Tm, 32, sm), M3 = msel(Tm, 33, sm);
        float V[4][4];           // [gp][x3]
        #pragma unroll
        for (int x3 = 0; x3 < 4; ++x3) {
            #pragma unroll
            for (int gp = 0; gp < 4; ++gp) V[gp][x3] = 0.f;
            #pragma unroll
            for (int x2 = 0; x2 < 4; ++x2) {
                float U[4];
                #pragma unroll
                for (int g = 0; g < 4; ++g)
                    U[g] = W[g * 4096 + SWZ((x2 + 4 * x3 + 16 * t) << 4)];
                #pragma unroll
                for (int gp = 0; gp < 4; ++gp)
                    #pragma unroll
                    for (int g = 0; g < 4; ++g)
                        V[gp][x3] += M2[gp * 64 + g * 4 + x2] * U[g];
            }
        }
        #pragma unroll
        for (int gp3 = 0; gp3 < 4; ++gp3) {
            float acc = 0.f;
            #pragma unroll
            for (int gp = 0; gp < 4; ++gp)
                #pragma unroll
                for (int x3 = 0; x3 < 4; ++x3)
                    acc += M3[gp3 * 64 + gp * 4 + x3] * V[gp][x3];
            W[gp3 * 4096 + SWZ(t << 8)] = acc;
        }
    }
    __syncthreads();
    // ---- row 5: (5,4)+(5,5) by thread 0 -> amplitude straight to out ----
    if (t == 0) {
        fcp M4 = msel(Tm, 34, sm), M5 = msel(Tm, 35, sm);
        float V[4][4];           // [gp][x5]
        #pragma unroll
        for (int x5 = 0; x5 < 4; ++x5) {
            #pragma unroll
            for (int gp = 0; gp < 4; ++gp) V[gp][x5] = 0.f;
            #pragma unroll
            for (int x4 = 0; x4 < 4; ++x4) {
                float U[4];
                #pragma unroll
                for (int g = 0; g < 4; ++g)
                    U[g] = W[g * 4096 + SWZ((x4 + 4 * x5) << 8)];
                #pragma unroll
                for (int gp = 0; gp < 4; ++gp)
                    #pragma unroll
                    for (int g = 0; g < 4; ++g)
                        V[gp][x5] += M4[gp * 64 + g * 4 + x4] * U[g];
            }
        }
        float r = 0.f;
        #pragma unroll
        for (int gp = 0; gp < 4; ++gp)
            #pragma unroll
            for (int x5 = 0; x5 < 4; ++x5)
                r += M5[gp * 4 + x5] * V[gp][x5];
        out[b] = r;
    }
}

extern "C" void kernel_launch(void* const* d_in, const int* in_sizes, int n_in,
                              void* d_out, int out_size, void* d_ws, size_t ws_size,
                              hipStream_t stream) {
    const int*   X  = (const int*)d_in[0];     // x: [1024, 36] int32
    const float* Tg = (const float*)d_in[1];   // T: [6,6,2,4,4,4,4] fp32
    float* out = (float*)d_out;                // reference output: float32
    float* Tm  = (float*)d_ws;                 // 73,728 B scratch
    (void)in_sizes; (void)n_in; (void)ws_size; (void)out_size;
    peps_reorder_kernel<<<dim3(72), dim3(256), 0, stream>>>(Tg, Tm);
    peps_amp_kernel<<<dim3(BATCH), dim3(256), 0, stream>>>(X, Tm, out);
}

// Round 13
// 178.223 us; speedup vs baseline: 1.1003x; 1.1003x over previous
//
#include <hip/hip_runtime.h>

#define NROW 6
#define NCOL 6
#define BATCH 1024
#define NSITE 36

// LDS bank-conflict swizzle: XOR dword-addr bits [4:2] with bits [7:5].
// Preserves bits [1:0]; constant within any aligned 4-dword window; SWZ(0)==0.
__device__ __forceinline__ int SWZ(int a) { return a ^ (((a >> 5) & 7) << 2); }

// Wave-uniform scalar-memory pointer: address_space(4) = AMDGPU constant.
// R13: M is read DIRECTLY from T (original layout) — the reorder kernel is
// gone. T[st][sp][x][gp][z][g]: coefficient (gp,z,g,x) sits at dword offset
// x*64 + gp*16 + z*4 + g from the site base. All offsets are compile-time
// constants off a wave-uniform base -> the compiler merges the scalar loads
// into s_load_dwordx4/x8/x16 batches (prior-session R12-proven path; the
// explicit vector-typed SMEM load of R12 was ill-formed: HIP_vector_type
// ctors can't bind address_space(4) references — scalar floats only).
// R4 (LDS-M) and R7 (VMEM-M) regressions still hold: M stays SMEM.
typedef const float __attribute__((address_space(4))) * fcp;

// Per-site base: T + (site*2+spin)*256  (T layout st*512+sp*256+...).
__device__ __forceinline__ fcp msel(const float* T, int step,
                                    unsigned long long sm) {
    int spin = (int)((sm >> step) & 1ull);
    return (fcp)(unsigned long long)(const void*)
        (T + (size_t)(step * 2 + spin) * 256);
}

// One MIDDLE-ROW step body (rows 1..4), 4 SPECTATORS PER THREAD — verbatim
// R9 arithmetic (harness-verified best, 150us amp). Only the M index
// expression changed: R9's Tm[(gp*4+z)*16 + g*4+x] == T[x*64+gp*16+z*4+g];
// loop order (z, g-outer, x-inner) and FMA order preserved ->
// bitwise-identical results.
template<int GIN, int GOUT, bool C0>
__device__ __forceinline__ void do_step4(float* __restrict__ W, const fcp Msf,
                                         const int* __restrict__ A)
{
    float in_s[4][16];           // [spectator][g*4+x]
    // ---- read phase ----
    if (C0) {                    // GIN==1; x is the low address digit
        #pragma unroll
        for (int i = 0; i < 4; ++i) {
            float4 q = *(const float4*)&W[A[i]];
            in_s[i][0] = q.x; in_s[i][1] = q.y;
            in_s[i][2] = q.z; in_s[i][3] = q.w;
        }
    } else {                     // spectator quad contiguous at A[x]
        #pragma unroll
        for (int g = 0; g < GIN; ++g)
            #pragma unroll
            for (int x = 0; x < 4; ++x) {
                float4 q = *(const float4*)&W[A[x] + g * 4096];
                in_s[0][g*4+x] = q.x; in_s[1][g*4+x] = q.y;
                in_s[2][g*4+x] = q.z; in_s[3][g*4+x] = q.w;
            }
    }
    // ---- compute + write (in-place; same address set) ----
    #pragma unroll
    for (int gp = 0; gp < GOUT; ++gp) {
        float a[4][4];
        #pragma unroll
        for (int z = 0; z < 4; ++z) {
            #pragma unroll
            for (int i = 0; i < 4; ++i) a[z][i] = 0.f;
            #pragma unroll
            for (int g = 0; g < GIN; ++g)
                #pragma unroll
                for (int x = 0; x < 4; ++x) {
                    // == R9's Msf[(gp*4+z)*16 + g*4 + x] under the transpose
                    const float m = Msf[x * 64 + gp * 16 + z * 4 + g];
                    #pragma unroll
                    for (int i = 0; i < 4; ++i)
                        a[z][i] += m * in_s[i][g*4+x];
                }
        }
        if (C0) {                // write per-spectator x-quads back
            #pragma unroll
            for (int i = 0; i < 4; ++i)
                *(float4*)&W[A[i] + gp * 4096] =
                    make_float4(a[0][i], a[1][i], a[2][i], a[3][i]);
        } else {
            #pragma unroll
            for (int z = 0; z < 4; ++z)
                *(float4*)&W[A[z] + gp * 4096] =
                    make_float4(a[z][0], a[z][1], a[z][2], a[z][3]);
        }
    }
}

// R13 = R9 (best verified: 150us amp / 186.6 total) with the reorder kernel
// eliminated (direct-T indexing, all offsets compile-time) and R10's
// mid_first fusion REVERTED (phase cost is critical-path-bound, not
// additive: long per-thread chains lose to short phases).
//   row 0     : fused chain, 3 cheap phases (R2/R9-verified algebra)
//   rows 1..4 : 6 in-place fixed-slot steps, 1 barrier each (R0/R9)
//   row 5     : fused chain, 3 tiny phases (R2/R9)
// State idx = g*4096 + SWZ(sum slot_j*4^j); 64KB LDS; 2 blocks/CU.
__global__ __launch_bounds__(256, 2)
void peps_amp_kernel(const int* __restrict__ X, const float* __restrict__ T,
                     float* __restrict__ out)
{
    __shared__ float W[16384];   // 65536 B exactly (4^7 fixed-slot state)

    const int b = blockIdx.x;
    const int t = threadIdx.x;
    const int u0 = 4 * t;        // this thread's spectators: u0..u0+3
    const int* xrow = X + b * NSITE;

    // PHYS=2: pack the 36 spins into one scalar 64-bit mask (SGPR-resident
    // so every T address below is provably wave-uniform).
    unsigned long long sm = 0ull;
    const int4* xp = (const int4*)xrow;
    #pragma unroll
    for (int k = 0; k < 9; ++k) {
        int4 v = xp[k];
        sm |= ((unsigned long long)(v.x & 1)) << (4 * k + 0);
        sm |= ((unsigned long long)(v.y & 1)) << (4 * k + 1);
        sm |= ((unsigned long long)(v.z & 1)) << (4 * k + 2);
        sm |= ((unsigned long long)(v.w & 1)) << (4 * k + 3);
    }
    {
        unsigned lo = __builtin_amdgcn_readfirstlane((int)(sm & 0xffffffffull));
        unsigned hi = __builtin_amdgcn_readfirstlane((int)(sm >> 32));
        sm = ((unsigned long long)hi << 32) | lo;
    }

    // ---- row 0: (0,0)+(0,1) by thread 0 ----
    // Tm[(gp*4+z)*16 + g*4+x]  ->  T[x*64 + gp*16 + z*4 + g]
    if (t == 0) {
        fcp T0 = msel(T, 0, sm), T1 = msel(T, 1, sm);
        float V[4][4];           // [gp][z0]  (seed state == 1.0; g=0,x=0)
        #pragma unroll
        for (int gp = 0; gp < 4; ++gp)
            #pragma unroll
            for (int z0 = 0; z0 < 4; ++z0)
                V[gp][z0] = T0[gp * 16 + z0 * 4];
        #pragma unroll
        for (int gp1 = 0; gp1 < 4; ++gp1)
            #pragma unroll
            for (int z1 = 0; z1 < 4; ++z1) {
                float o[4];
                #pragma unroll
                for (int z0 = 0; z0 < 4; ++z0) {
                    float acc = 0.f;
                    #pragma unroll
                    for (int gp = 0; gp < 4; ++gp)   // g=gp, x=0
                        acc += T1[gp1 * 16 + z1 * 4 + gp] * V[gp][z0];
                    o[z0] = acc;
                }
                *(float4*)&W[gp1 * 4096 + SWZ(4 * z1)] =
                    make_float4(o[0], o[1], o[2], o[3]);
            }
    }
    __syncthreads();
    // ---- row 0: (0,2)+(0,3) by 16 threads (t = z0 + 4*z1) ----
    if (t < 16) {
        fcp T2 = msel(T, 2, sm), T3 = msel(T, 3, sm);
        float U[4];
        #pragma unroll
        for (int g = 0; g < 4; ++g) U[g] = W[g * 4096 + SWZ(t)];
        float V[4][4];           // [gp][z2]
        #pragma unroll
        for (int gp = 0; gp < 4; ++gp)
            #pragma unroll
            for (int z2 = 0; z2 < 4; ++z2) {
                float acc = 0.f;
                #pragma unroll
                for (int g = 0; g < 4; ++g)          // x=0
                    acc += T2[gp * 16 + z2 * 4 + g] * U[g];
                V[gp][z2] = acc;
            }
        #pragma unroll
        for (int gp3 = 0; gp3 < 4; ++gp3)
            #pragma unroll
            for (int z3 = 0; z3 < 4; ++z3)
                #pragma unroll
                for (int z2 = 0; z2 < 4; ++z2) {
                    float acc = 0.f;
                    #pragma unroll
                    for (int gp = 0; gp < 4; ++gp)   // g=gp, x=0
                        acc += T3[gp3 * 16 + z3 * 4 + gp] * V[gp][z2];
                    W[gp3 * 4096 + SWZ(t + 16 * z2 + 64 * z3)] = acc;
                }
    }
    __syncthreads();
    // ---- row 0: (0,4)+(0,5) by all 256 threads (g collapses -> plane 0) --
    {
        fcp T4 = msel(T, 4, sm), T5 = msel(T, 5, sm);
        float U[4];
        #pragma unroll
        for (int g = 0; g < 4; ++g) U[g] = W[g * 4096 + SWZ(t)];
        float V[4][4];           // [gp][z4]
        #pragma unroll
        for (int gp = 0; gp < 4; ++gp)
            #pragma unroll
            for (int z4 = 0; z4 < 4; ++z4) {
                float acc = 0.f;
                #pragma unroll
                for (int g = 0; g < 4; ++g)          // x=0
                    acc += T4[gp * 16 + z4 * 4 + g] * U[g];
                V[gp][z4] = acc;
            }
        #pragma unroll
        for (int z5 = 0; z5 < 4; ++z5)
            #pragma unroll
            for (int z4 = 0; z4 < 4; ++z4) {
                float acc = 0.f;
                #pragma unroll
                for (int gp = 0; gp < 4; ++gp)       // gp'=0: g=gp, x=0
                    acc += T5[z5 * 4 + gp] * V[gp][z4];
                W[SWZ(t + 256 * z4 + 1024 * z5)] = acc;    // plane 0
            }
    }

    // ---- rows 1..4: 6 in-place steps each, 1 barrier/step (R9) ----
    int step = 6;
    for (int row = 1; row <= 4; ++row) {
        for (int c = 0; c < NCOL; ++c, ++step) {
            const int lowb = 2 * c;
            const int p4c = 1 << (2 * c);
            const int lowmask = (1 << lowb) - 1;
            const fcp Msf = msel(T, step, sm);

            __syncthreads();     // the ONLY barrier per step

            int A[4];
            if (c == 0) {
                #pragma unroll
                for (int i = 0; i < 4; ++i) A[i] = SWZ(16 * t + 4 * i);
            } else {
                const int mr0 = ((u0 >> lowb) << (2 * c + 2)) | (u0 & lowmask);
                #pragma unroll
                for (int d = 0; d < 4; ++d) A[d] = SWZ(d * p4c + mr0);
            }

            if (c == 0)            do_step4<1,4,true >(W, Msf, A);
            else if (c < NCOL - 1) do_step4<4,4,false>(W, Msf, A);
            else                   do_step4<4,1,false>(W, Msf, A);
        }
    }

    // ---- row 5: (5,0)+(5,1) by all 256 threads ----
    // Row-5 Tm[gp*64 + g*4 + x]  ->  T[x*64 + gp*16 + g]   (z=0)
    __syncthreads();
    {
        fcp T30 = msel(T, 30, sm), T31 = msel(T, 31, sm);
        const int base = t << 4;
        float V[4][4];           // [gp][x1]
        #pragma unroll
        for (int x1 = 0; x1 < 4; ++x1) {
            float4 q = *(const float4*)&W[SWZ(base + 4 * x1)];
            float U[4] = {q.x, q.y, q.z, q.w};
            #pragma unroll
            for (int gp = 0; gp < 4; ++gp) {
                float acc = 0.f;
                #pragma unroll
                for (int x0 = 0; x0 < 4; ++x0)      // g=0
                    acc += T30[x0 * 64 + gp * 16] * U[x0];
                V[gp][x1] = acc;
            }
        }
        #pragma unroll
        for (int gp1 = 0; gp1 < 4; ++gp1) {
            float acc = 0.f;
            #pragma unroll
            for (int gp = 0; gp < 4; ++gp)
                #pragma unroll
                for (int x1 = 0; x1 < 4; ++x1)      // g=gp
                    acc += T31[x1 * 64 + gp1 * 16 + gp] * V[gp][x1];
            W[gp1 * 4096 + SWZ(base)] = acc;
        }
    }
    __syncthreads();
    // ---- row 5: (5,2)+(5,3) by 16 threads (t = x4 + 4*x5) ----
    if (t < 16) {
        fcp T32 = msel(T, 32, sm), T33 = msel(T, 33, sm);
        float V[4][4];           // [gp][x3]
        #pragma unroll
        for (int x3 = 0; x3 < 4; ++x3) {
            #pragma unroll
            for (int gp = 0; gp < 4; ++gp) V[gp][x3] = 0.f;
            #pragma unroll
            for (int x2 = 0; x2 < 4; ++x2) {
                float U[4];
                #pragma unroll
                for (int g = 0; g < 4; ++g)
                    U[g] = W[g * 4096 + SWZ((x2 + 4 * x3 + 16 * t) << 4)];
                #pragma unroll
                for (int gp = 0; gp < 4; ++gp)
                    #pragma unroll
                    for (int g = 0; g < 4; ++g)
                        V[gp][x3] += T32[x2 * 64 + gp * 16 + g] * U[g];
            }
        }
        #pragma unroll
        for (int gp3 = 0; gp3 < 4; ++gp3) {
            float acc = 0.f;
            #pragma unroll
            for (int gp = 0; gp < 4; ++gp)
                #pragma unroll
                for (int x3 = 0; x3 < 4; ++x3)      // g=gp
                    acc += T33[x3 * 64 + gp3 * 16 + gp] * V[gp][x3];
            W[gp3 * 4096 + SWZ(t << 8)] = acc;
        }
    }
    __syncthreads();
    // ---- row 5: (5,4)+(5,5) by thread 0 -> amplitude straight to out ----
    if (t == 0) {
        fcp T34 = msel(T, 34, sm), T35 = msel(T, 35, sm);
        float V[4][4];           // [gp][x5]
        #pragma unroll
        for (int x5 = 0; x5 < 4; ++x5) {
            #pragma unroll
            for (int gp = 0; gp < 4; ++gp) V[gp][x5] = 0.f;
            #pragma unroll
            for (int x4 = 0; x4 < 4; ++x4) {
                float U[4];
                #pragma unroll
                for (int g = 0; g < 4; ++g)
                    U[g] = W[g * 4096 + SWZ((x4 + 4 * x5) << 8)];
                #pragma unroll
                for (int gp = 0; gp < 4; ++gp)
                    #pragma unroll
                    for (int g = 0; g < 4; ++g)
                        V[gp][x5] += T34[x4 * 64 + gp * 16 + g] * U[g];
            }
        }
        float r = 0.f;
        #pragma unroll
        for (int gp = 0; gp < 4; ++gp)
            #pragma unroll
            for (int x5 = 0; x5 < 4; ++x5)          // gp'=0: g=gp
                r += T35[x5 * 64 + gp] * V[gp][x5];
        out[b] = r;
    }
}

extern "C" void kernel_launch(void* const* d_in, const int* in_sizes, int n_in,
                              void* d_out, int out_size, void* d_ws, size_t ws_size,
                              hipStream_t stream) {
    const int*   X  = (const int*)d_in[0];     // x: [1024, 36] int32
    const float* Tg = (const float*)d_in[1];   // T: [6,6,2,4,4,4,4] fp32
    float* out = (float*)d_out;                // reference output: float32
    (void)in_sizes; (void)n_in; (void)ws_size; (void)out_size; (void)d_ws;
    // single kernel: M is indexed directly from T (no reorder pass)
    peps_amp_kernel<<<dim3(BATCH), dim3(256), 0, stream>>>(X, Tg, out);
}